// Round 6
// baseline (404.944 us; speedup 1.0000x reference)
//
#include <hip/hip_runtime.h>
#include <hip/hip_bf16.h>
#include <math.h>

#define R_N 8192
#define D_K 4096
#define C_N 80
#define NC2 160          // both heads concatenated
#define KSPLIT 8
#define KSLICE (D_K / KSPLIT)   // 512
#define KPRE 512
#define TOPK 100
#define LIST_CAP (80 * 512)

typedef _Float16 f16;
typedef f16 f16x2 __attribute__((ext_vector_type(2)));
typedef f16 f16x8 __attribute__((ext_vector_type(8)));
typedef float f32x4 __attribute__((ext_vector_type(4)));
typedef unsigned long long u64;

__device__ __forceinline__ void async_copy16(const void* g, void* l) {
    __builtin_amdgcn_global_load_lds(
        (const __attribute__((address_space(1))) void*)g,
        (__attribute__((address_space(3))) void*)l, 16, 0, 0);
}

// ---------------------------------------------------------------------------
// init: blocks 0..639 zero d_out (+g_cnt); blocks 640..767 transpose W into
// hi/lo f16 BhT/BlT[n][k] (n: 0..79=Wc, 80..159=Wd) via LDS, coalesced.
// ---------------------------------------------------------------------------
__global__ __launch_bounds__(256) void init_kernel(const float* __restrict__ Wc,
                                                   const float* __restrict__ Wd,
                                                   float* __restrict__ out,
                                                   unsigned* __restrict__ cnt,
                                                   f16* __restrict__ BhT,
                                                   f16* __restrict__ BlT) {
    const int b = blockIdx.x, tid = threadIdx.x;
    if (b < 640) {
        ((float4*)out)[b * 256 + tid] = make_float4(0.f, 0.f, 0.f, 0.f);
        if (b == 0 && tid == 0) *cnt = 0u;
        return;
    }
    __shared__ float Ws[32 * 161];   // [k-row][160 cols], pad 161 -> conflict-free out-reads
    const int kb = b - 640;          // 0..127
    const int k0 = kb * 32;
    for (int i = tid; i < 1280; i += 256) {
        int row = i / 40, q = i % 40;
        const float* src = (q < 20) ? (Wc + (size_t)(k0 + row) * C_N + q * 4)
                                    : (Wd + (size_t)(k0 + row) * C_N + (q - 20) * 4);
        float4 t4 = *(const float4*)src;
        int cc = (q < 20) ? q * 4 : 80 + (q - 20) * 4;
        Ws[row * 161 + cc + 0] = t4.x; Ws[row * 161 + cc + 1] = t4.y;
        Ws[row * 161 + cc + 2] = t4.z; Ws[row * 161 + cc + 3] = t4.w;
    }
    __syncthreads();
    const int g = tid >> 4, l = tid & 15;   // 16 groups x 16 lanes
#pragma unroll
    for (int p = 0; p < 10; ++p) {
        int n = p * 16 + g;
        float v0 = Ws[(2 * l) * 161 + n];
        float v1 = Ws[(2 * l + 1) * 161 + n];
        f16 h0 = (f16)v0, h1 = (f16)v1;
        f16 l0 = (f16)(v0 - (float)h0), l1 = (f16)(v1 - (float)h1);
        *(f16x2*)&BhT[(size_t)n * D_K + k0 + 2 * l] = (f16x2){h0, h1};
        *(f16x2*)&BlT[(size_t)n * D_K + k0 + 2 * l] = (f16x2){l0, l1};
    }
}

// ---------------------------------------------------------------------------
// fused dual GEMM via f16 split-2 MFMA (al*bh + ah*bl + ah*bh), K-split into
// fp32 partials [KSPLIT][R][160]. grid: 64 row-blocks x 8 K-slices, 4 waves.
// 2x2 wave tiling: wave (wm,wn) owns rows wm*64..+64, cols wn*80..+80.
// ---------------------------------------------------------------------------
__global__ __launch_bounds__(256) void gemm_part(const float* __restrict__ x,
                                                 const f16* __restrict__ BhT,
                                                 const f16* __restrict__ BlT,
                                                 float* __restrict__ part) {
    __shared__ __align__(16) float As[128 * 32];   // [r][32k], 16B chunks XOR-swizzled
    __shared__ __align__(16) f16 Bhs[160 * 32];    // [nn][32k] contiguous
    __shared__ __align__(16) f16 Bls[160 * 32];

    const int b    = blockIdx.x;
    const int rb   = b & 63;
    const int ks   = b >> 6;
    const int row0 = rb * 128;
    const int kbase = ks * KSLICE;
    const int tid  = threadIdx.x;
    const int wv   = tid >> 6, lane = tid & 63;
    const int wm   = wv & 1, wn = wv >> 1;
    const int m    = lane & 15, quad = lane >> 4;

    f32x4 acc[4][5];
#pragma unroll
    for (int t = 0; t < 4; ++t)
#pragma unroll
        for (int n = 0; n < 5; ++n) acc[t][n] = (f32x4)(0.0f);

    for (int ch = 0; ch < KSLICE / 32; ++ch) {
        const int k0 = kbase + ch * 32;
        // ---- A DMA: 128 rows x 32 fp32 = 1024 16B-chunks, XOR swizzle ----
#pragma unroll
        for (int i = 0; i < 4; ++i) {
            int t = tid + 256 * i;
            int r = t >> 3, cs = t & 7;
            int cg = cs ^ (r & 7);
            async_copy16(x + (size_t)(row0 + r) * D_K + k0 + cg * 4,
                         (char*)As + (size_t)t * 16);
        }
        // ---- B DMA: 160 rows x 32 f16 (64B) = 640 16B-chunks, hi+lo ----
#pragma unroll
        for (int i = 0; i < 3; ++i) {
            int t = tid + 256 * i;
            if (t < 640) {
                int nn = t >> 2, cc = t & 3;
                size_t go = (size_t)nn * D_K + k0 + cc * 8;
                async_copy16(BhT + go, (char*)Bhs + (size_t)t * 16);
                async_copy16(BlT + go, (char*)Bls + (size_t)t * 16);
            }
        }
        __syncthreads();
        // ---- A fragments: read fp32, split hi/lo in registers ----
        f16x8 ah[4], al[4];
#pragma unroll
        for (int t = 0; t < 4; ++t) {
            int r = wm * 64 + t * 16 + m;
            int r7 = r & 7;
            float4 c0 = *(const float4*)&As[r * 32 + (((2 * quad) ^ r7) << 2)];
            float4 c1 = *(const float4*)&As[r * 32 + (((2 * quad + 1) ^ r7) << 2)];
            float tv[8] = {c0.x, c0.y, c0.z, c0.w, c1.x, c1.y, c1.z, c1.w};
#pragma unroll
            for (int j = 0; j < 8; ++j) {
                f16 h = (f16)tv[j];
                ah[t][j] = h;
                al[t][j] = (f16)(tv[j] - (float)h);
            }
        }
        // ---- MFMA ----
#pragma unroll
        for (int n = 0; n < 5; ++n) {
            int nn = (wn * 5 + n) * 16 + m;
            f16x8 bh = *(const f16x8*)&Bhs[nn * 32 + quad * 8];
            f16x8 bl = *(const f16x8*)&Bls[nn * 32 + quad * 8];
#pragma unroll
            for (int t = 0; t < 4; ++t) {
                acc[t][n] = __builtin_amdgcn_mfma_f32_16x16x32_f16(al[t], bh, acc[t][n], 0, 0, 0);
                acc[t][n] = __builtin_amdgcn_mfma_f32_16x16x32_f16(ah[t], bl, acc[t][n], 0, 0, 0);
                acc[t][n] = __builtin_amdgcn_mfma_f32_16x16x32_f16(ah[t], bh, acc[t][n], 0, 0, 0);
            }
        }
        __syncthreads();
    }
    // ---- epilogue: scatter C/D fragments to partials ----
#pragma unroll
    for (int t = 0; t < 4; ++t) {
        int grow0 = row0 + wm * 64 + t * 16 + quad * 4;
#pragma unroll
        for (int n = 0; n < 5; ++n) {
            int gcol = (wn * 5 + n) * 16 + m;
#pragma unroll
            for (int r4 = 0; r4 < 4; ++r4)
                part[((size_t)ks * R_N + grow0 + r4) * NC2 + gcol] = acc[t][n][r4];
        }
    }
}

// ---------------------------------------------------------------------------
// reduce K-split partials (pairwise tree, deterministic), add bias, route
// ---------------------------------------------------------------------------
__global__ __launch_bounds__(256) void reduce_bias(const float* __restrict__ part,
                                                   const float* __restrict__ bc,
                                                   const float* __restrict__ bd,
                                                   float* __restrict__ cls,
                                                   float* __restrict__ detT) {
    const size_t STRIDE = (size_t)R_N * NC2;
    size_t idx = (size_t)blockIdx.x * 256 + threadIdx.x;
    int row = (int)(idx / NC2), col = (int)(idx % NC2);
    float p0 = part[idx + 0 * STRIDE], p1 = part[idx + 1 * STRIDE];
    float p2 = part[idx + 2 * STRIDE], p3 = part[idx + 3 * STRIDE];
    float p4 = part[idx + 4 * STRIDE], p5 = part[idx + 5 * STRIDE];
    float p6 = part[idx + 6 * STRIDE], p7 = part[idx + 7 * STRIDE];
    float s = ((p0 + p1) + (p2 + p3)) + ((p4 + p5) + (p6 + p7));
    if (col < C_N) {
        cls[(size_t)row * C_N + col] = s + bc[col];
    } else {
        detT[(size_t)(col - C_N) * R_N + row] = s + bd[col - C_N];
    }
}

// ---------------------------------------------------------------------------
// softmax over classes (axis=1); writes result transposed into Pt [C][R]
// ---------------------------------------------------------------------------
__global__ __launch_bounds__(256) void row_softmax(const float* __restrict__ cls,
                                                   float* __restrict__ Pt) {
    int tid = threadIdx.x;
    int wave = tid >> 6, lane = tid & 63;
    int row = blockIdx.x * 4 + wave;
    float v0 = cls[(size_t)row * C_N + lane];
    float v1 = (lane < 16) ? cls[(size_t)row * C_N + 64 + lane] : -INFINITY;
    float m = fmaxf(v0, v1);
#pragma unroll
    for (int off = 32; off > 0; off >>= 1) m = fmaxf(m, __shfl_xor(m, off, 64));
    float e0 = expf(v0 - m);
    float e1 = (lane < 16) ? expf(v1 - m) : 0.0f;
    float s = e0 + e1;
#pragma unroll
    for (int off = 32; off > 0; off >>= 1) s += __shfl_xor(s, off, 64);
    Pt[(size_t)lane * R_N + row] = e0 / s;
    if (lane < 16) Pt[(size_t)(64 + lane) * R_N + row] = e1 / s;
}

// ---------------------------------------------------------------------------
// per-class max + sum(exp) over proposals (identical reduction order to the
// former col_softmax_mul passes 1-2)
// ---------------------------------------------------------------------------
__global__ __launch_bounds__(256) void col_stats(const float* __restrict__ detT,
                                                 float* __restrict__ cm,
                                                 float* __restrict__ csum) {
    __shared__ float red[256];
    int c = blockIdx.x, tid = threadIdx.x;
    const float* dc = detT + (size_t)c * R_N;
    float m = -INFINITY;
    for (int r = tid; r < R_N; r += 256) m = fmaxf(m, dc[r]);
    red[tid] = m; __syncthreads();
    for (int s2 = 128; s2 > 0; s2 >>= 1) {
        if (tid < s2) red[tid] = fmaxf(red[tid], red[tid + s2]);
        __syncthreads();
    }
    m = red[0]; __syncthreads();
    float sum = 0.0f;
    for (int r = tid; r < R_N; r += 256) sum += expf(dc[r] - m);
    red[tid] = sum; __syncthreads();
    for (int s2 = 128; s2 > 0; s2 >>= 1) {
        if (tid < s2) red[tid] += red[tid + s2];
        __syncthreads();
    }
    if (tid == 0) { cm[c] = m; csum[c] = red[0]; }
}

// ---------------------------------------------------------------------------
// Stage A: per (class, chunk of 1024) compute final score inline
// (Pt * exp(det-m)/s — bit-identical to the former materialized P), bitonic
// sort composite keys (score_bits<<32)|(8191-r), emit sorted top-512.
// ---------------------------------------------------------------------------
__global__ __launch_bounds__(256) void chunk_sort(const float* __restrict__ Pt,
                                                  const float* __restrict__ detT,
                                                  const float* __restrict__ cm,
                                                  const float* __restrict__ csum,
                                                  unsigned long long* __restrict__ cand) {
    __shared__ u64 sk[1024];
    const int c = blockIdx.x >> 3, ch = blockIdx.x & 7;
    const int tid = threadIdx.x;
    const float m = cm[c], s = csum[c];
    const float* pc = Pt + (size_t)c * R_N + ch * 1024;
    const float* dc = detT + (size_t)c * R_N + ch * 1024;

    for (int i = tid; i < 1024; i += 256) {
        float val = pc[i] * (expf(dc[i] - m) / s);
        unsigned u = __float_as_uint(val);
        int r = ch * 1024 + i;
        sk[i] = ((u64)u << 32) | (unsigned)(8191 - r);
    }
    __syncthreads();
    for (int size = 2; size <= 1024; size <<= 1) {
        for (int stride = size >> 1; stride > 0; stride >>= 1) {
            for (int t = tid; t < 512; t += 256) {
                int i = 2 * t - (t & (stride - 1));
                int j = i + stride;
                u64 a = sk[i], b = sk[j];
                bool desc = ((i & size) == 0);
                if ((a < b) == desc) { sk[i] = b; sk[j] = a; }
            }
            __syncthreads();
        }
    }
    u64* dst = cand + (size_t)blockIdx.x * 512;
    for (int i = tid; i < 512; i += 256) dst[i] = sk[i];
}

// ---------------------------------------------------------------------------
// Stage B (fused): merge 8 sorted lists -> class top-512; clip boxes; IoU
// suppression mask in LDS; greedy scan; append kept to global list + k100.
// one block per class.
// ---------------------------------------------------------------------------
__global__ __launch_bounds__(256) void merge_nms(const u64* __restrict__ cand,
                                                 const float* __restrict__ boxes,
                                                 float* __restrict__ g_ls,
                                                 unsigned* __restrict__ g_lp,
                                                 unsigned* __restrict__ g_cnt,
                                                 float* __restrict__ k100) {
    __shared__ u64 A[1024];
    __shared__ float sx1[512], sy1[512], sx2[512], sy2[512], sar[512], svals[512];
    __shared__ int sridx[512];
    __shared__ u64 msk[512 * 8];   // 32 KB
    __shared__ unsigned char keepf[512];
    __shared__ int s_nv;

    const int c = blockIdx.x, tid = threadIdx.x;
    const u64* base = cand + (size_t)c * 8 * 512;

    // ---- 7 bitonic merges ----
    for (int i = tid; i < 512; i += 256) A[i] = base[i];
    for (int l2 = 1; l2 < 8; ++l2) {
        __syncthreads();
        for (int i = tid; i < 512; i += 256) A[512 + i] = base[l2 * 512 + (511 - i)];
        __syncthreads();
        for (int stride = 512; stride > 0; stride >>= 1) {
            for (int t = tid; t < 512; t += 256) {
                int i = 2 * t - (t & (stride - 1));
                int j = i + stride;
                u64 a = A[i], b = A[j];
                if (a < b) { A[i] = b; A[j] = a; }
            }
            __syncthreads();
        }
    }
    __syncthreads();
    // ---- extract + clip + valid-prefix length ----
    for (int i = tid; i < 512; i += 256) {
        u64 k = A[i];
        float v = __uint_as_float((unsigned)(k >> 32));
        int r = 8191 - (int)(k & 0xFFFFFFFFull);
        svals[i] = v; sridx[i] = r;
        float b0 = boxes[r * 4 + 0], b1 = boxes[r * 4 + 1];
        float b2 = boxes[r * 4 + 2], b3 = boxes[r * 4 + 3];
        float x1 = fminf(fmaxf(b0, 0.0f), 1000.0f);
        float y1 = fminf(fmaxf(b1, 0.0f), 800.0f);
        float x2 = fminf(fmaxf(b2, 0.0f), 1000.0f);
        float y2 = fminf(fmaxf(b3, 0.0f), 800.0f);
        sx1[i] = x1; sy1[i] = y1; sx2[i] = x2; sy2[i] = y2;
        sar[i] = (x2 - x1) * (y2 - y1);
        float vn = (i < 511) ? __uint_as_float((unsigned)(A[i + 1] >> 32)) : -1.0f;
        if (v > 1e-5f && !(vn > 1e-5f)) s_nv = i + 1;
        if (i == 0 && !(v > 1e-5f)) s_nv = 0;
    }
    __syncthreads();
    const int nv = s_nv;
    // ---- suppression bitmask (LDS) ----
    for (int task = tid; task < 512 * 8; task += 256) {
        int i = task >> 3, w = task & 7;
        u64 bits = 0ull;
        if (i < nv && w <= (i >> 6)) {
            float xi1 = sx1[i], yi1 = sy1[i], xi2 = sx2[i], yi2 = sy2[i], ai = sar[i];
#pragma unroll 8
            for (int j2 = 0; j2 < 64; ++j2) {
                int j = (w << 6) + j2;
                float xx1 = fmaxf(xi1, sx1[j]);
                float yy1 = fmaxf(yi1, sy1[j]);
                float xx2 = fminf(xi2, sx2[j]);
                float yy2 = fminf(yi2, sy2[j]);
                float ww = fmaxf(xx2 - xx1, 0.0f);
                float hh = fmaxf(yy2 - yy1, 0.0f);
                float inter = ww * hh;
                float iou = inter / (ai + sar[j] - inter + 1e-9f);
                if (iou > 0.5f) bits |= (1ull << j2);
            }
        }
        msk[i * 8 + w] = bits;
    }
    __syncthreads();
    // ---- greedy scan (wave 0), 8-deep LDS prefetch ----
    if (tid < 64) {
        const int lane = tid;
        const bool rd = (lane < 8);
        u64 keptw = 0ull;
        u64 pf[8];
#pragma unroll
        for (int d = 0; d < 8; ++d) pf[d] = rd ? msk[(d & 511) * 8 + lane] : 0ull;
        for (int i = 0; i < nv; ++i) {
            u64 mm = pf[i & 7];
            int ip = (i + 8) & 511;
            pf[i & 7] = rd ? msk[ip * 8 + lane] : 0ull;
            int sup = __any((keptw & mm) != 0ull);
            int keep = !sup;
            if (keep && lane == (i >> 6)) keptw |= (1ull << (i & 63));
            if (lane == 0) keepf[i] = (unsigned char)keep;
        }
        // ---- per-class top-100 kept (desc by construction), 0-padded ----
        for (int i = lane; i < 100; i += 64) k100[c * 100 + i] = 0.0f;
        unsigned base2 = 0;
        for (int ch2 = 0; ch2 < 8 && (int)base2 < 100; ++ch2) {
            int i = ch2 * 64 + lane;
            bool kk = (i < nv) && (keepf[i] != 0);
            u64 mb = __ballot(kk);
            unsigned pre = (unsigned)__popcll(mb & ((1ull << lane) - 1ull));
            if (kk && base2 + pre < 100)
                k100[c * 100 + base2 + pre] = svals[i];
            base2 += (unsigned)__popcll(mb);
        }
    }
    __syncthreads();
    // ---- append kept detections to global list ----
    for (int i = tid; i < nv; i += 256) {
        if (keepf[i]) {
            unsigned pos = atomicAdd(g_cnt, 1u);
            g_ls[pos] = svals[i];
            g_lp[pos] = (unsigned)(sridx[i] * C_N + c);
        }
    }
}

// ---------------------------------------------------------------------------
// kth = 100th largest over k100 candidates (registers + value binary search)
// ---------------------------------------------------------------------------
__global__ __launch_bounds__(256) void kth_kernel(const float* __restrict__ k100,
                                                  float* __restrict__ g_kth) {
    __shared__ unsigned red[4];
    __shared__ unsigned s_total;
    const int tid = threadIdx.x;
    const int wv = tid >> 6, lane = tid & 63;
    unsigned v[32];
#pragma unroll
    for (int j = 0; j < 32; ++j) {
        int idx = j * 256 + tid;
        v[j] = (idx < C_N * 100) ? __float_as_uint(k100[idx]) : 0u;
    }
    unsigned lo = 0u, hi = 0x7FFFFFFFu;
    while (lo < hi) {
        unsigned mid = lo + (hi - lo + 1) / 2;
        unsigned cnt = 0;
#pragma unroll
        for (int j = 0; j < 32; ++j) cnt += (v[j] >= mid) ? 1u : 0u;
#pragma unroll
        for (int off = 32; off > 0; off >>= 1) cnt += __shfl_down(cnt, off, 64);
        if (lane == 0) red[wv] = cnt;
        __syncthreads();
        if (tid == 0) s_total = red[0] + red[1] + red[2] + red[3];
        __syncthreads();
        unsigned total = s_total;
        if (total >= (unsigned)TOPK) lo = mid; else hi = mid - 1;
    }
    if (tid == 0) *g_kth = __uint_as_float(lo);
}

// ---------------------------------------------------------------------------
// scatter kept scores >= kth into zeroed output [R, C]
// ---------------------------------------------------------------------------
__global__ __launch_bounds__(256) void scatter_kernel(const float* __restrict__ g_ls,
                                                      const unsigned* __restrict__ g_lp,
                                                      const unsigned* __restrict__ g_cnt,
                                                      const float* __restrict__ g_kth,
                                                      float* __restrict__ out) {
    unsigned idx = blockIdx.x * 256 + threadIdx.x;
    unsigned n = *g_cnt;
    float kth = *g_kth;
    if (idx < n) {
        float s = g_ls[idx];
        if (s >= kth) out[g_lp[idx]] = s;
    }
}

// ---------------------------------------------------------------------------
extern "C" void kernel_launch(void* const* d_in, const int* in_sizes, int n_in,
                              void* d_out, int out_size, void* d_ws, size_t ws_size,
                              hipStream_t stream) {
    const float* x     = (const float*)d_in[0];
    const float* Wc    = (const float*)d_in[1];
    const float* bc    = (const float*)d_in[2];
    const float* Wd    = (const float*)d_in[3];
    const float* bd    = (const float*)d_in[4];
    const float* boxes = (const float*)d_in[5];
    float* out = (float*)d_out;

    char* w = (char*)d_ws;
    float* part = (float*)w;  w += (size_t)KSPLIT * R_N * NC2 * sizeof(float);   // 41.9 MB (dead after reduce_bias)
    float* cls  = (float*)w;  w += (size_t)R_N * C_N * sizeof(float);
    float* detT = (float*)w;  w += (size_t)C_N * R_N * sizeof(float);
    float* Pt   = (float*)w;  w += (size_t)C_N * R_N * sizeof(float);
    float* g_ls = (float*)w;  w += (size_t)LIST_CAP * sizeof(float);
    unsigned* g_lp = (unsigned*)w; w += (size_t)LIST_CAP * sizeof(unsigned);
    unsigned* g_cnt = (unsigned*)w; w += 256;
    float* g_kth = (float*)w; w += 256;
    f16* BhT = (f16*)w; w += (size_t)NC2 * D_K * sizeof(f16);   // 1.31 MB
    f16* BlT = (f16*)w; w += (size_t)NC2 * D_K * sizeof(f16);   // 1.31 MB
    float* k100 = (float*)w; w += (size_t)C_N * 100 * sizeof(float);
    float* cm   = (float*)w; w += 1024;
    float* csum = (float*)w; w += 1024;

    // NMS candidate buffer aliases the dead `part` region (used after reduce_bias)
    u64* cand = (u64*)part;   // 2.62 MB

    init_kernel<<<768, 256, 0, stream>>>(Wc, Wd, out, g_cnt, BhT, BlT);
    gemm_part<<<64 * KSPLIT, 256, 0, stream>>>(x, BhT, BlT, part);
    reduce_bias<<<(R_N * NC2) / 256, 256, 0, stream>>>(part, bc, bd, cls, detT);
    row_softmax<<<R_N / 4, 256, 0, stream>>>(cls, Pt);
    col_stats<<<C_N, 256, 0, stream>>>(detT, cm, csum);
    chunk_sort<<<C_N * 8, 256, 0, stream>>>(Pt, detT, cm, csum, cand);
    merge_nms<<<C_N, 256, 0, stream>>>(cand, boxes, g_ls, g_lp, g_cnt, k100);
    kth_kernel<<<1, 256, 0, stream>>>(k100, g_kth);
    scatter_kernel<<<(LIST_CAP + 255) / 256, 256, 0, stream>>>(g_ls, g_lp, g_cnt, g_kth, out);
}

// Round 7
// 377.558 us; speedup vs baseline: 1.0725x; 1.0725x over previous
//
#include <hip/hip_runtime.h>
#include <hip/hip_bf16.h>
#include <math.h>

#define R_N 8192
#define D_K 4096
#define C_N 80
#define NC2 160          // both heads concatenated
#define KSPLIT 8
#define KSLICE (D_K / KSPLIT)   // 512
#define KPRE 512
#define TOPK 100
#define LIST_CAP (80 * 512)

typedef _Float16 f16;
typedef f16 f16x2 __attribute__((ext_vector_type(2)));
typedef f16 f16x8 __attribute__((ext_vector_type(8)));
typedef float f32x4 __attribute__((ext_vector_type(4)));
typedef unsigned long long u64;

__device__ __forceinline__ void async_copy16(const void* g, void* l) {
    __builtin_amdgcn_global_load_lds(
        (const __attribute__((address_space(1))) void*)g,
        (__attribute__((address_space(3))) void*)l, 16, 0, 0);
}

// ---------------------------------------------------------------------------
// init: blocks 0..639 zero d_out (+g_cnt); blocks 640..767 transpose W into
// hi/lo f16 BhT/BlT[n][k] (n: 0..79=Wc, 80..159=Wd) via LDS, coalesced.
// ---------------------------------------------------------------------------
__global__ __launch_bounds__(256) void init_kernel(const float* __restrict__ Wc,
                                                   const float* __restrict__ Wd,
                                                   float* __restrict__ out,
                                                   unsigned* __restrict__ cnt,
                                                   f16* __restrict__ BhT,
                                                   f16* __restrict__ BlT) {
    const int b = blockIdx.x, tid = threadIdx.x;
    if (b < 640) {
        ((float4*)out)[b * 256 + tid] = make_float4(0.f, 0.f, 0.f, 0.f);
        if (b == 0 && tid == 0) *cnt = 0u;
        return;
    }
    __shared__ float Ws[32 * 161];   // [k-row][160 cols], pad 161 -> conflict-free out-reads
    const int kb = b - 640;          // 0..127
    const int k0 = kb * 32;
    for (int i = tid; i < 1280; i += 256) {
        int row = i / 40, q = i % 40;
        const float* src = (q < 20) ? (Wc + (size_t)(k0 + row) * C_N + q * 4)
                                    : (Wd + (size_t)(k0 + row) * C_N + (q - 20) * 4);
        float4 t4 = *(const float4*)src;
        int cc = (q < 20) ? q * 4 : 80 + (q - 20) * 4;
        Ws[row * 161 + cc + 0] = t4.x; Ws[row * 161 + cc + 1] = t4.y;
        Ws[row * 161 + cc + 2] = t4.z; Ws[row * 161 + cc + 3] = t4.w;
    }
    __syncthreads();
    const int g = tid >> 4, l = tid & 15;   // 16 groups x 16 lanes
#pragma unroll
    for (int p = 0; p < 10; ++p) {
        int n = p * 16 + g;
        float v0 = Ws[(2 * l) * 161 + n];
        float v1 = Ws[(2 * l + 1) * 161 + n];
        f16 h0 = (f16)v0, h1 = (f16)v1;
        f16 l0 = (f16)(v0 - (float)h0), l1 = (f16)(v1 - (float)h1);
        *(f16x2*)&BhT[(size_t)n * D_K + k0 + 2 * l] = (f16x2){h0, h1};
        *(f16x2*)&BlT[(size_t)n * D_K + k0 + 2 * l] = (f16x2){l0, l1};
    }
}

// ---------------------------------------------------------------------------
// fused dual GEMM via f16 split-2 MFMA (al*bh + ah*bl + ah*bh), K-split into
// fp32 partials [KSPLIT][R][160]. grid: 64 row-blocks x 8 K-slices, 4 waves.
// 2x2 wave tiling: wave (wm,wn) owns rows wm*64..+64, cols wn*80..+80.
// ---------------------------------------------------------------------------
__global__ __launch_bounds__(256) void gemm_part(const float* __restrict__ x,
                                                 const f16* __restrict__ BhT,
                                                 const f16* __restrict__ BlT,
                                                 float* __restrict__ part) {
    __shared__ __align__(16) float As[128 * 32];   // [r][32k], 16B chunks XOR-swizzled
    __shared__ __align__(16) f16 Bhs[160 * 32];    // [nn][32k] contiguous
    __shared__ __align__(16) f16 Bls[160 * 32];

    const int b    = blockIdx.x;
    const int rb   = b & 63;
    const int ks   = b >> 6;
    const int row0 = rb * 128;
    const int kbase = ks * KSLICE;
    const int tid  = threadIdx.x;
    const int wv   = tid >> 6, lane = tid & 63;
    const int wm   = wv & 1, wn = wv >> 1;
    const int m    = lane & 15, quad = lane >> 4;

    f32x4 acc[4][5];
#pragma unroll
    for (int t = 0; t < 4; ++t)
#pragma unroll
        for (int n = 0; n < 5; ++n) acc[t][n] = (f32x4)(0.0f);

    for (int ch = 0; ch < KSLICE / 32; ++ch) {
        const int k0 = kbase + ch * 32;
        // ---- A DMA: 128 rows x 32 fp32 = 1024 16B-chunks, XOR swizzle ----
#pragma unroll
        for (int i = 0; i < 4; ++i) {
            int t = tid + 256 * i;
            int r = t >> 3, cs = t & 7;
            int cg = cs ^ (r & 7);
            async_copy16(x + (size_t)(row0 + r) * D_K + k0 + cg * 4,
                         (char*)As + (size_t)t * 16);
        }
        // ---- B DMA: 160 rows x 32 f16 (64B) = 640 16B-chunks, hi+lo ----
#pragma unroll
        for (int i = 0; i < 3; ++i) {
            int t = tid + 256 * i;
            if (t < 640) {
                int nn = t >> 2, cc = t & 3;
                size_t go = (size_t)nn * D_K + k0 + cc * 8;
                async_copy16(BhT + go, (char*)Bhs + (size_t)t * 16);
                async_copy16(BlT + go, (char*)Bls + (size_t)t * 16);
            }
        }
        __syncthreads();
        // ---- A fragments: read fp32, split hi/lo in registers ----
        f16x8 ah[4], al[4];
#pragma unroll
        for (int t = 0; t < 4; ++t) {
            int r = wm * 64 + t * 16 + m;
            int r7 = r & 7;
            float4 c0 = *(const float4*)&As[r * 32 + (((2 * quad) ^ r7) << 2)];
            float4 c1 = *(const float4*)&As[r * 32 + (((2 * quad + 1) ^ r7) << 2)];
            float tv[8] = {c0.x, c0.y, c0.z, c0.w, c1.x, c1.y, c1.z, c1.w};
#pragma unroll
            for (int j = 0; j < 8; ++j) {
                f16 h = (f16)tv[j];
                ah[t][j] = h;
                al[t][j] = (f16)(tv[j] - (float)h);
            }
        }
        // ---- MFMA ----
#pragma unroll
        for (int n = 0; n < 5; ++n) {
            int nn = (wn * 5 + n) * 16 + m;
            f16x8 bh = *(const f16x8*)&Bhs[nn * 32 + quad * 8];
            f16x8 bl = *(const f16x8*)&Bls[nn * 32 + quad * 8];
#pragma unroll
            for (int t = 0; t < 4; ++t) {
                acc[t][n] = __builtin_amdgcn_mfma_f32_16x16x32_f16(al[t], bh, acc[t][n], 0, 0, 0);
                acc[t][n] = __builtin_amdgcn_mfma_f32_16x16x32_f16(ah[t], bl, acc[t][n], 0, 0, 0);
                acc[t][n] = __builtin_amdgcn_mfma_f32_16x16x32_f16(ah[t], bh, acc[t][n], 0, 0, 0);
            }
        }
        __syncthreads();
    }
    // ---- epilogue: scatter C/D fragments to partials ----
#pragma unroll
    for (int t = 0; t < 4; ++t) {
        int grow0 = row0 + wm * 64 + t * 16 + quad * 4;
#pragma unroll
        for (int n = 0; n < 5; ++n) {
            int gcol = (wn * 5 + n) * 16 + m;
#pragma unroll
            for (int r4 = 0; r4 < 4; ++r4)
                part[((size_t)ks * R_N + grow0 + r4) * NC2 + gcol] = acc[t][n][r4];
        }
    }
}

// ---------------------------------------------------------------------------
// reduce K-split partials (pairwise tree, deterministic), add bias, route
// ---------------------------------------------------------------------------
__global__ __launch_bounds__(256) void reduce_bias(const float* __restrict__ part,
                                                   const float* __restrict__ bc,
                                                   const float* __restrict__ bd,
                                                   float* __restrict__ cls,
                                                   float* __restrict__ detT) {
    const size_t STRIDE = (size_t)R_N * NC2;
    size_t idx = (size_t)blockIdx.x * 256 + threadIdx.x;
    int row = (int)(idx / NC2), col = (int)(idx % NC2);
    float p0 = part[idx + 0 * STRIDE], p1 = part[idx + 1 * STRIDE];
    float p2 = part[idx + 2 * STRIDE], p3 = part[idx + 3 * STRIDE];
    float p4 = part[idx + 4 * STRIDE], p5 = part[idx + 5 * STRIDE];
    float p6 = part[idx + 6 * STRIDE], p7 = part[idx + 7 * STRIDE];
    float s = ((p0 + p1) + (p2 + p3)) + ((p4 + p5) + (p6 + p7));
    if (col < C_N) {
        cls[(size_t)row * C_N + col] = s + bc[col];
    } else {
        detT[(size_t)(col - C_N) * R_N + row] = s + bd[col - C_N];
    }
}

// ---------------------------------------------------------------------------
// softmax over classes (axis=1); writes result transposed into Pt [C][R]
// ---------------------------------------------------------------------------
__global__ __launch_bounds__(256) void row_softmax(const float* __restrict__ cls,
                                                   float* __restrict__ Pt) {
    int tid = threadIdx.x;
    int wave = tid >> 6, lane = tid & 63;
    int row = blockIdx.x * 4 + wave;
    float v0 = cls[(size_t)row * C_N + lane];
    float v1 = (lane < 16) ? cls[(size_t)row * C_N + 64 + lane] : -INFINITY;
    float m = fmaxf(v0, v1);
#pragma unroll
    for (int off = 32; off > 0; off >>= 1) m = fmaxf(m, __shfl_xor(m, off, 64));
    float e0 = expf(v0 - m);
    float e1 = (lane < 16) ? expf(v1 - m) : 0.0f;
    float s = e0 + e1;
#pragma unroll
    for (int off = 32; off > 0; off >>= 1) s += __shfl_xor(s, off, 64);
    Pt[(size_t)lane * R_N + row] = e0 / s;
    if (lane < 16) Pt[(size_t)(64 + lane) * R_N + row] = e1 / s;
}

// ---------------------------------------------------------------------------
// per-class max + sum(exp) over proposals (identical reduction order to the
// original col_softmax passes 1-2)
// ---------------------------------------------------------------------------
__global__ __launch_bounds__(256) void col_stats(const float* __restrict__ detT,
                                                 float* __restrict__ cm,
                                                 float* __restrict__ csum) {
    __shared__ float red[256];
    int c = blockIdx.x, tid = threadIdx.x;
    const float* dc = detT + (size_t)c * R_N;
    float m = -INFINITY;
    for (int r = tid; r < R_N; r += 256) m = fmaxf(m, dc[r]);
    red[tid] = m; __syncthreads();
    for (int s2 = 128; s2 > 0; s2 >>= 1) {
        if (tid < s2) red[tid] = fmaxf(red[tid], red[tid + s2]);
        __syncthreads();
    }
    m = red[0]; __syncthreads();
    float sum = 0.0f;
    for (int r = tid; r < R_N; r += 256) sum += expf(dc[r] - m);
    red[tid] = sum; __syncthreads();
    for (int s2 = 128; s2 > 0; s2 >>= 1) {
        if (tid < s2) red[tid] += red[tid + s2];
        __syncthreads();
    }
    if (tid == 0) { cm[c] = m; csum[c] = red[0]; }
}

// ---------------------------------------------------------------------------
// Stage A: per (class, chunk of 1024) compute final score inline, bitonic
// sort composite keys (score_bits<<32)|(8191-r), emit sorted top-512.
// ---------------------------------------------------------------------------
__global__ __launch_bounds__(256) void chunk_sort(const float* __restrict__ Pt,
                                                  const float* __restrict__ detT,
                                                  const float* __restrict__ cm,
                                                  const float* __restrict__ csum,
                                                  u64* __restrict__ cand) {
    __shared__ u64 sk[1024];
    const int c = blockIdx.x >> 3, ch = blockIdx.x & 7;
    const int tid = threadIdx.x;
    const float m = cm[c], s = csum[c];
    const float* pc = Pt + (size_t)c * R_N + ch * 1024;
    const float* dc = detT + (size_t)c * R_N + ch * 1024;

    for (int i = tid; i < 1024; i += 256) {
        float val = pc[i] * (expf(dc[i] - m) / s);
        unsigned u = __float_as_uint(val);
        int r = ch * 1024 + i;
        sk[i] = ((u64)u << 32) | (unsigned)(8191 - r);
    }
    __syncthreads();
    for (int size = 2; size <= 1024; size <<= 1) {
        for (int stride = size >> 1; stride > 0; stride >>= 1) {
            for (int t = tid; t < 512; t += 256) {
                int i = 2 * t - (t & (stride - 1));
                int j = i + stride;
                u64 a = sk[i], b = sk[j];
                bool desc = ((i & size) == 0);
                if ((a < b) == desc) { sk[i] = b; sk[j] = a; }
            }
            __syncthreads();
        }
    }
    u64* dst = cand + (size_t)blockIdx.x * 512;
    for (int i = tid; i < 512; i += 256) dst[i] = sk[i];
}

// ---------------------------------------------------------------------------
// Stage B1: pairwise merge 8 sorted lists -> 4. grid = 80*4: (class, pair q).
// ---------------------------------------------------------------------------
__global__ __launch_bounds__(256) void merge4(const u64* __restrict__ cand,
                                              u64* __restrict__ cand2) {
    __shared__ u64 A[1024];
    const int c = blockIdx.x >> 2, q = blockIdx.x & 3;
    const int tid = threadIdx.x;
    const u64* b0 = cand + ((size_t)c * 8 + 2 * q) * 512;
    const u64* b1 = cand + ((size_t)c * 8 + 2 * q + 1) * 512;
    for (int i = tid; i < 512; i += 256) {
        A[i] = b0[i];
        A[512 + i] = b1[511 - i];   // reversed -> bitonic
    }
    __syncthreads();
    for (int stride = 512; stride > 0; stride >>= 1) {
        for (int t = tid; t < 512; t += 256) {
            int i = 2 * t - (t & (stride - 1));
            int j = i + stride;
            u64 a = A[i], b = A[j];
            if (a < b) { A[i] = b; A[j] = a; }
        }
        __syncthreads();
    }
    u64* dst = cand2 + ((size_t)c * 4 + q) * 512;
    for (int i = tid; i < 512; i += 256) dst[i] = A[i];
}

// ---------------------------------------------------------------------------
// Stage B2: fold 4 sorted lists -> exact class top-512; extract vals/ridx/
// clipped boxes + valid-prefix length. grid = 80 blocks.
// ---------------------------------------------------------------------------
__global__ __launch_bounds__(256) void merge_extract4(const u64* __restrict__ cand2,
                                                      const float* __restrict__ boxes,
                                                      float* __restrict__ svals,
                                                      int* __restrict__ sridx,
                                                      float* __restrict__ cbox,
                                                      int* __restrict__ nvalid) {
    __shared__ u64 A[1024];
    const int c = blockIdx.x, tid = threadIdx.x;
    const u64* base = cand2 + (size_t)c * 4 * 512;

    for (int i = tid; i < 512; i += 256) A[i] = base[i];
    for (int l = 1; l < 4; ++l) {
        __syncthreads();
        for (int i = tid; i < 512; i += 256) A[512 + i] = base[l * 512 + (511 - i)];
        __syncthreads();
        for (int stride = 512; stride > 0; stride >>= 1) {
            for (int t = tid; t < 512; t += 256) {
                int i = 2 * t - (t & (stride - 1));
                int j = i + stride;
                u64 a = A[i], b = A[j];
                if (a < b) { A[i] = b; A[j] = a; }
            }
            __syncthreads();
        }
    }
    __syncthreads();
    for (int i = tid; i < 512; i += 256) {
        u64 k = A[i];
        float v = __uint_as_float((unsigned)(k >> 32));
        int r = 8191 - (int)(k & 0xFFFFFFFFull);
        svals[c * 512 + i] = v;
        sridx[c * 512 + i] = r;
        float b0 = boxes[r * 4 + 0], b1 = boxes[r * 4 + 1];
        float b2 = boxes[r * 4 + 2], b3 = boxes[r * 4 + 3];
        float4 cb;
        cb.x = fminf(fmaxf(b0, 0.0f), 1000.0f);
        cb.y = fminf(fmaxf(b1, 0.0f), 800.0f);
        cb.z = fminf(fmaxf(b2, 0.0f), 1000.0f);
        cb.w = fminf(fmaxf(b3, 0.0f), 800.0f);
        *(float4*)&cbox[((size_t)c * 512 + i) * 4] = cb;
        float vn = (i < 511) ? __uint_as_float((unsigned)(A[i + 1] >> 32)) : -1.0f;
        if (v > 1e-5f && !(vn > 1e-5f)) nvalid[c] = i + 1;
        if (i == 0 && !(v > 1e-5f)) nvalid[c] = 0;
    }
}

// ---------------------------------------------------------------------------
// Stage C: suppression bitmask to global. grid = 80*8: (class, word w).
// ---------------------------------------------------------------------------
__global__ __launch_bounds__(256) void iou_mask(const float* __restrict__ cbox,
                                                const int* __restrict__ nvalid,
                                                u64* __restrict__ gmask) {
    __shared__ float sx1[512], sy1[512], sx2[512], sy2[512], sar[512];
    const int c = blockIdx.x >> 3, w = blockIdx.x & 7;
    const int tid = threadIdx.x;
    const int nv = nvalid[c];

    for (int i = tid; i < 512; i += 256) {
        float4 b = *(const float4*)&cbox[((size_t)c * 512 + i) * 4];
        sx1[i] = b.x; sy1[i] = b.y; sx2[i] = b.z; sy2[i] = b.w;
        sar[i] = (b.z - b.x) * (b.w - b.y);
    }
    __syncthreads();
    for (int i = tid; i < 512; i += 256) {
        u64 bits = 0ull;
        if (i < nv && w <= (i >> 6)) {
            float xi1 = sx1[i], yi1 = sy1[i], xi2 = sx2[i], yi2 = sy2[i], ai = sar[i];
#pragma unroll 8
            for (int j2 = 0; j2 < 64; ++j2) {
                int j = (w << 6) + j2;
                float xx1 = fmaxf(xi1, sx1[j]);
                float yy1 = fmaxf(yi1, sy1[j]);
                float xx2 = fminf(xi2, sx2[j]);
                float yy2 = fminf(yi2, sy2[j]);
                float ww = fmaxf(xx2 - xx1, 0.0f);
                float hh = fmaxf(yy2 - yy1, 0.0f);
                float inter = ww * hh;
                float iou = inter / (ai + sar[j] - inter + 1e-9f);
                if (iou > 0.5f) bits |= (1ull << j2);
            }
        }
        gmask[((size_t)c * 512 + i) * 8 + w] = bits;
    }
}

// ---------------------------------------------------------------------------
// Stage D: greedy scan, one wave per class, prefetched LDS mask.
// Also compacts the first 100 kept scores (desc) into k100[c][100], 0-padded.
// ---------------------------------------------------------------------------
__global__ __launch_bounds__(64) void nms_scan(const u64* __restrict__ gmask,
                                               const float* __restrict__ svals,
                                               const int* __restrict__ sridx,
                                               const int* __restrict__ nvalid,
                                               float* __restrict__ g_ls,
                                               unsigned* __restrict__ g_lp,
                                               unsigned* __restrict__ g_cnt,
                                               float* __restrict__ k100) {
    __shared__ u64 sm[512 * 8];
    __shared__ unsigned char keepf[512];
    const int c = blockIdx.x, lane = threadIdx.x;
    const int nv = nvalid[c];
    const u64* gm = gmask + (size_t)c * 512 * 8;

    for (int t = lane; t < 4096; t += 64) sm[t] = gm[t];
    __syncthreads();

    const bool rd = (lane < 8);
    u64 keptw = 0ull;
    u64 pf[8];
#pragma unroll
    for (int d = 0; d < 8; ++d) pf[d] = rd ? sm[(d & 511) * 8 + lane] : 0ull;
    for (int i = 0; i < nv; ++i) {
        u64 mm = pf[i & 7];
        int ip = (i + 8) & 511;
        pf[i & 7] = rd ? sm[ip * 8 + lane] : 0ull;
        int sup = __any((keptw & mm) != 0ull);
        int keep = !sup;
        if (keep && lane == (i >> 6)) keptw |= (1ull << (i & 63));
        if (lane == 0) keepf[i] = (unsigned char)keep;
    }
    __syncthreads();
    for (int i = lane; i < nv; i += 64) {
        if (keepf[i]) {
            unsigned pos = atomicAdd(g_cnt, 1u);
            g_ls[pos] = svals[c * 512 + i];
            g_lp[pos] = (unsigned)(sridx[c * 512 + i] * C_N + c);
        }
    }
    // ---- per-class top-100 kept candidates (desc by construction), 0-pad ----
    for (int i = lane; i < 100; i += 64) k100[c * 100 + i] = 0.0f;
    unsigned base = 0;
    for (int ch2 = 0; ch2 < 8 && (int)base < 100; ++ch2) {
        int i = ch2 * 64 + lane;
        bool kk = (i < nv) && (keepf[i] != 0);
        u64 mb = __ballot(kk);
        unsigned pre = (unsigned)__popcll(mb & ((1ull << lane) - 1ull));
        if (kk && base + pre < 100)
            k100[c * 100 + base + pre] = svals[c * 512 + i];
        base += (unsigned)__popcll(mb);
    }
}

// ---------------------------------------------------------------------------
// kth = 100th largest over k100 candidates (registers + value binary search)
// ---------------------------------------------------------------------------
__global__ __launch_bounds__(256) void kth_kernel(const float* __restrict__ k100,
                                                  float* __restrict__ g_kth) {
    __shared__ unsigned red[4];
    __shared__ unsigned s_total;
    const int tid = threadIdx.x;
    const int wv = tid >> 6, lane = tid & 63;
    unsigned v[32];
#pragma unroll
    for (int j = 0; j < 32; ++j) {
        int idx = j * 256 + tid;
        v[j] = (idx < C_N * 100) ? __float_as_uint(k100[idx]) : 0u;
    }
    unsigned lo = 0u, hi = 0x7FFFFFFFu;
    while (lo < hi) {
        unsigned mid = lo + (hi - lo + 1) / 2;
        unsigned cnt = 0;
#pragma unroll
        for (int j = 0; j < 32; ++j) cnt += (v[j] >= mid) ? 1u : 0u;
#pragma unroll
        for (int off = 32; off > 0; off >>= 1) cnt += __shfl_down(cnt, off, 64);
        if (lane == 0) red[wv] = cnt;
        __syncthreads();
        if (tid == 0) s_total = red[0] + red[1] + red[2] + red[3];
        __syncthreads();
        unsigned total = s_total;
        if (total >= (unsigned)TOPK) lo = mid; else hi = mid - 1;
    }
    if (tid == 0) *g_kth = __uint_as_float(lo);
}

// ---------------------------------------------------------------------------
// scatter kept scores >= kth into zeroed output [R, C]
// ---------------------------------------------------------------------------
__global__ __launch_bounds__(256) void scatter_kernel(const float* __restrict__ g_ls,
                                                      const unsigned* __restrict__ g_lp,
                                                      const unsigned* __restrict__ g_cnt,
                                                      const float* __restrict__ g_kth,
                                                      float* __restrict__ out) {
    unsigned idx = blockIdx.x * 256 + threadIdx.x;
    unsigned n = *g_cnt;
    float kth = *g_kth;
    if (idx < n) {
        float s = g_ls[idx];
        if (s >= kth) out[g_lp[idx]] = s;
    }
}

// ---------------------------------------------------------------------------
extern "C" void kernel_launch(void* const* d_in, const int* in_sizes, int n_in,
                              void* d_out, int out_size, void* d_ws, size_t ws_size,
                              hipStream_t stream) {
    const float* x     = (const float*)d_in[0];
    const float* Wc    = (const float*)d_in[1];
    const float* bc    = (const float*)d_in[2];
    const float* Wd    = (const float*)d_in[3];
    const float* bd    = (const float*)d_in[4];
    const float* boxes = (const float*)d_in[5];
    float* out = (float*)d_out;

    char* w = (char*)d_ws;
    float* part = (float*)w;  w += (size_t)KSPLIT * R_N * NC2 * sizeof(float);   // 41.9 MB (dead after reduce_bias)
    float* cls  = (float*)w;  w += (size_t)R_N * C_N * sizeof(float);
    float* detT = (float*)w;  w += (size_t)C_N * R_N * sizeof(float);
    float* Pt   = (float*)w;  w += (size_t)C_N * R_N * sizeof(float);
    float* g_ls = (float*)w;  w += (size_t)LIST_CAP * sizeof(float);
    unsigned* g_lp = (unsigned*)w; w += (size_t)LIST_CAP * sizeof(unsigned);
    unsigned* g_cnt = (unsigned*)w; w += 256;
    float* g_kth = (float*)w; w += 256;
    f16* BhT = (f16*)w; w += (size_t)NC2 * D_K * sizeof(f16);   // 1.31 MB
    f16* BlT = (f16*)w; w += (size_t)NC2 * D_K * sizeof(f16);   // 1.31 MB
    float* k100 = (float*)w; w += (size_t)C_N * 100 * sizeof(float);
    float* cm   = (float*)w; w += 1024;
    float* csum = (float*)w; w += 1024;

    // NMS scratch aliases the dead `part` region (first use is after reduce_bias)
    char* a = (char*)part;
    u64* cand  = (u64*)a; a += (size_t)C_N * 8 * 512 * sizeof(u64);   // 2.62 MB
    u64* cand2 = (u64*)a; a += (size_t)C_N * 4 * 512 * sizeof(u64);   // 1.31 MB
    float* svals = (float*)a;  a += (size_t)C_N * KPRE * sizeof(float);
    int*   sridx = (int*)a;    a += (size_t)C_N * KPRE * sizeof(int);
    float* cbox  = (float*)a;  a += (size_t)C_N * KPRE * 4 * sizeof(float);
    int*   nvalid = (int*)a;   a += 4096;
    u64* gmask = (u64*)a; a += (size_t)C_N * KPRE * 8 * sizeof(u64);  // 2.62 MB

    init_kernel<<<768, 256, 0, stream>>>(Wc, Wd, out, g_cnt, BhT, BlT);
    gemm_part<<<64 * KSPLIT, 256, 0, stream>>>(x, BhT, BlT, part);
    reduce_bias<<<(R_N * NC2) / 256, 256, 0, stream>>>(part, bc, bd, cls, detT);
    row_softmax<<<R_N / 4, 256, 0, stream>>>(cls, Pt);
    col_stats<<<C_N, 256, 0, stream>>>(detT, cm, csum);
    chunk_sort<<<C_N * 8, 256, 0, stream>>>(Pt, detT, cm, csum, cand);
    merge4<<<C_N * 4, 256, 0, stream>>>(cand, cand2);
    merge_extract4<<<C_N, 256, 0, stream>>>(cand2, boxes, svals, sridx, cbox, nvalid);
    iou_mask<<<C_N * 8, 256, 0, stream>>>(cbox, nvalid, gmask);
    nms_scan<<<C_N, 64, 0, stream>>>(gmask, svals, sridx, nvalid, g_ls, g_lp, g_cnt, k100);
    kth_kernel<<<1, 256, 0, stream>>>(k100, g_kth);
    scatter_kernel<<<(LIST_CAP + 255) / 256, 256, 0, stream>>>(g_ls, g_lp, g_cnt, g_kth, out);
}